// Round 4
// baseline (295.329 us; speedup 1.0000x reference)
//
#include <hip/hip_runtime.h>
#include <math.h>

#define Bn 2
#define Hn 12
#define Tn 512
#define Cn 768
#define HS 64
#define BH 24
#define MTOP 8
#define NCOMB 36
#define NEGV -1e30f

// combo tables: slots (0..7) for size-1 (8 combos) then size-2 (28 combos), lexicographic
__device__ __constant__ int C_SL0[NCOMB] = {
  0,1,2,3,4,5,6,7,
  0,0,0,0,0,0,0,
  1,1,1,1,1,1,
  2,2,2,2,2,
  3,3,3,3,
  4,4,4,
  5,5,
  6};
__device__ __constant__ int C_SL1[NCOMB] = {
  -1,-1,-1,-1,-1,-1,-1,-1,
  1,2,3,4,5,6,7,
  2,3,4,5,6,7,
  3,4,5,6,7,
  4,5,6,7,
  5,6,7,
  6,7,
  7};

// gram pair tables: 45 pairs (a<=b) over 9 tokens
__device__ __constant__ int PA[45] = {
  0,0,0,0,0,0,0,0,0,
  1,1,1,1,1,1,1,1,
  2,2,2,2,2,2,2,
  3,3,3,3,3,3,
  4,4,4,4,4,
  5,5,5,5,
  6,6,6,
  7,7,
  8};
__device__ __constant__ int PB[45] = {
  0,1,2,3,4,5,6,7,8,
  1,2,3,4,5,6,7,8,
  2,3,4,5,6,7,8,
  3,4,5,6,7,8,
  4,5,6,7,8,
  5,6,7,8,
  6,7,8,
  7,8,
  8};

// ---------------- split-K 64x64-tile fp32 GEMM: out += A @ W^T (+ bias on slice 0) ----
// NSLAB = K-slabs (of 16) per slice; blockIdx.z = slice. Epilogue: fp32 atomicAdd.
// SCATTER=true: qkv scatter to per-head q/k/v; false: plain row-major.
template<int NSLAB, bool SCATTER>
__global__ __launch_bounds__(256) void gemm64(const float* __restrict__ A,
                                              const float* __restrict__ W,
                                              const float* __restrict__ bias,
                                              float* __restrict__ out,
                                              float* __restrict__ qh,
                                              float* __restrict__ kh,
                                              float* __restrict__ vh) {
    __shared__ float As[16][68];   // As[kk][m]
    __shared__ float Bs[16][68];   // Bs[kk][n]
    const int tn = blockIdx.x * 64;
    const int tm = blockIdx.y * 64;
    const int kz = blockIdx.z;
    const int tid = threadIdx.x;
    const int tx = tid & 15;       // n dir
    const int ty = tid >> 4;       // m dir
    const int lm  = tid >> 2;      // staging row (0..63)
    const int lkc = (tid & 3) * 4; // staging k offset (0,4,8,12)

    const float* pA = A + (size_t)(tm + lm) * Cn + kz * (NSLAB * 16) + lkc;
    const float* pB = W + (size_t)(tn + lm) * Cn + kz * (NSLAB * 16) + lkc;
    float4 ra = *(const float4*)pA;
    float4 rb = *(const float4*)pB;

    float acc[4][4] = {};
    for (int k0 = 0; k0 < NSLAB * 16; k0 += 16) {
        As[lkc+0][lm] = ra.x; As[lkc+1][lm] = ra.y; As[lkc+2][lm] = ra.z; As[lkc+3][lm] = ra.w;
        Bs[lkc+0][lm] = rb.x; Bs[lkc+1][lm] = rb.y; Bs[lkc+2][lm] = rb.z; Bs[lkc+3][lm] = rb.w;
        __syncthreads();
        if (k0 + 16 < NSLAB * 16) {    // prefetch next K-slab
            ra = *(const float4*)(pA + k0 + 16);
            rb = *(const float4*)(pB + k0 + 16);
        }
        #pragma unroll
        for (int kk = 0; kk < 16; ++kk) {
            float4 a4 = *(const float4*)&As[kk][ty * 4];
            float4 b4 = *(const float4*)&Bs[kk][tx * 4];
            float am[4] = {a4.x, a4.y, a4.z, a4.w};
            float bn[4] = {b4.x, b4.y, b4.z, b4.w};
            #pragma unroll
            for (int um = 0; um < 4; ++um)
                #pragma unroll
                for (int un = 0; un < 4; ++un)
                    acc[um][un] += am[um] * bn[un];
        }
        __syncthreads();
    }

    float bv[4] = {0.f, 0.f, 0.f, 0.f};
    if (kz == 0) {
        #pragma unroll
        for (int un = 0; un < 4; ++un) bv[un] = bias[tn + tx * 4 + un];
    }

    if (!SCATTER) {
        #pragma unroll
        for (int um = 0; um < 4; ++um) {
            int m = tm + ty * 4 + um;
            float* row = out + (size_t)m * Cn + tn + tx * 4;
            #pragma unroll
            for (int un = 0; un < 4; ++un)
                atomicAdd(row + un, acc[um][un] + bv[un]);
        }
    } else {
        // 64-col tile lies entirely within one qkv part and one head
        const int part = tn / Cn;
        const int c0 = tn - part * Cn;
        const int h = c0 >> 6;
        const int d = tx * 4;
        float* dst = (part == 0) ? qh : ((part == 1) ? kh : vh);
        #pragma unroll
        for (int um = 0; um < 4; ++um) {
            int m = tm + ty * 4 + um;
            int bb = m >> 9, t = m & 511;
            float* row = dst + ((size_t)((bb * Hn) + h) * Tn + t) * HS + d;
            #pragma unroll
            for (int un = 0; un < 4; ++un)
                atomicAdd(row + un, acc[um][un] + bv[un]);
        }
    }
}

// ---------------- DPP selection: one WAVE per token, 4 consecutive tokens/block -------
// K-prefix scanned via shared LDS chunks (4-way reuse), register-prefetch pipelined.
__global__ __launch_bounds__(256, 4) void dpp_kernel(const float* __restrict__ qh,
                                                     const float* __restrict__ kh,
                                                     const float* __restrict__ vh,
                                                     float* __restrict__ yflat) {
    const int bh = blockIdx.x;
    const int i0 = blockIdx.y * 4;
    const int w = threadIdx.x >> 6;
    const int lane = threadIdx.x & 63;
    const int i = i0 + w;

    __shared__ float Klds[64][68];     // K-chunk staging (17.4 KB)
    __shared__ float Ksh[4][9][68];    // selected K rows (b128 gram reads)
    __shared__ float Vsh[4][9][65];    // selected V rows (b32 lane-stride reads)
    __shared__ float Gsh[4][81];
    __shared__ float qdsh[4][12];
    __shared__ float PW[4][36][4];

    const float* qp    = qh + (size_t)(bh * Tn + i) * HS;
    const float* kbase = kh + (size_t)bh * Tn * HS;
    const float* vbase = vh + (size_t)bh * Tn * HS;

    // q_i resident in registers for the whole sim phase
    float4 qv[16];
    #pragma unroll
    for (int t = 0; t < 16; ++t) qv[t] = ((const float4*)qp)[t];

    float sv[8];
    #pragma unroll
    for (int r = 0; r < 8; ++r) sv[r] = -INFINITY;

    const int cmax = (i0 + 3) >> 6;    // block-uniform
    const int rmax = i >> 6;

    // software-pipelined chunk staging: prefetch chunk c+1 while computing chunk c
    float4 pre[4];
    {
        const float4* src = (const float4*)kbase;
        #pragma unroll
        for (int u = 0; u < 4; ++u) pre[u] = src[threadIdx.x + u * 256];
    }
    #pragma unroll
    for (int c = 0; c < 8; ++c) {
        if (c <= cmax) {
            #pragma unroll
            for (int u = 0; u < 4; ++u) {
                int e = threadIdx.x + u * 256;
                *(float4*)&Klds[e >> 4][(e & 15) * 4] = pre[u];
            }
            __syncthreads();
            if (c + 1 <= cmax) {
                const float4* src = (const float4*)(kbase + (size_t)(c + 1) * 64 * HS);
                #pragma unroll
                for (int u = 0; u < 4; ++u) pre[u] = src[threadIdx.x + u * 256];
            }
            if (c <= rmax) {
                const int j = c * 64 + lane;
                const float4* kr = (const float4*)&Klds[lane][0];
                float acc = 0.f;
                #pragma unroll
                for (int t = 0; t < 16; ++t) {
                    float4 kv = kr[t];
                    acc += kv.x * qv[t].x; acc += kv.y * qv[t].y;
                    acc += kv.z * qv[t].z; acc += kv.w * qv[t].w;
                }
                sv[c] = (j <= i) ? acc : -INFINITY;
            }
            __syncthreads();
        }
    }

    // qd0 = sim[i] = k_i . q_i
    float qd0 = 0.f;
    #pragma unroll
    for (int c = 0; c < 8; ++c) {
        float t = __shfl(sv[c], i & 63, 64);
        if (c == rmax) qd0 = t;
    }

    // top-8: 8 in-register butterfly argmax passes (value desc, tie -> lower index)
    float topv[8]; int topi[8];
    #pragma unroll
    for (int p = 0; p < MTOP; ++p) {
        float bv = -INFINITY; int bi = 0x7fffffff;
        #pragma unroll
        for (int r = 0; r < 8; ++r) {
            int j = r * 64 + lane;
            float v = sv[r];
            if (v > bv || (v == bv && j < bi)) { bv = v; bi = j; }
        }
        #pragma unroll
        for (int off = 32; off > 0; off >>= 1) {
            float ov = __shfl_xor(bv, off, 64);
            int   oi = __shfl_xor(bi, off, 64);
            if (ov > bv || (ov == bv && oi < bi)) { bv = ov; bi = oi; }
        }
        topv[p] = bv; topi[p] = bi;
        const int rs = bi >> 6, ls = bi & 63;
        #pragma unroll
        for (int r = 0; r < 8; ++r)
            if (r == rs && lane == ls) sv[r] = -INFINITY;
    }

    // validity bitmask per slot (wave-uniform)
    const int n_cand = (i + 1 < MTOP) ? (i + 1) : MTOP;
    int vmask = 0;
    #pragma unroll
    for (int s = 0; s < MTOP; ++s)
        if (s < n_cand && topi[s] != i) vmask |= (1 << s);

    // stage selected K/V rows {i} U top_idx (coalesced, lane = d)
    #pragma unroll
    for (int a = 0; a < 9; ++a) {
        int t = (a == 0) ? i : topi[a - 1];
        Ksh[w][a][lane] = kbase[(size_t)t * HS + lane];
        Vsh[w][a][lane] = vbase[(size_t)t * HS + lane];
    }
    if (lane < 9) {
        float val = qd0;
        #pragma unroll
        for (int p = 0; p < 8; ++p) if (lane == p + 1) val = topv[p];
        qdsh[w][lane] = val;
    }
    __syncthreads();

    // gram: lane l < 45 computes pair (PA[l], PB[l])
    if (lane < 45) {
        const int a = PA[lane], b = PB[lane];
        const float4* rka = (const float4*)&Ksh[w][a][0];
        const float4* rkb = (const float4*)&Ksh[w][b][0];
        float acc = 0.f;
        #pragma unroll
        for (int t = 0; t < 16; ++t) {
            float4 fa = rka[t], fb = rkb[t];
            acc += fa.x * fb.x; acc += fa.y * fb.y;
            acc += fa.z * fb.z; acc += fa.w * fb.w;
        }
        Gsh[w][a * 9 + b] = acc;
        Gsh[w][b * 9 + a] = acc;
    }
    __syncthreads();

    // combos on lanes 0..35
    float score = -INFINITY;
    int ca = 0, cb = 0, sdim = 1;
    if (lane < NCOMB) {
        const int sl0 = C_SL0[lane], sl1 = C_SL1[lane];
        sdim = (sl1 < 0) ? 1 : 2;
        ca = sl0 + 1;
        cb = (sl1 < 0) ? 0 : sl1 + 1;
        bool valid = ((vmask >> sl0) & 1);
        if (sdim == 2) valid = valid && ((vmask >> sl1) & 1);
        float G00 = Gsh[w][0];
        float Gaa = Gsh[w][ca * 9 + ca];
        float G0a = Gsh[w][ca];
        float det;
        if (sdim == 1) {
            det = G00 * Gaa - G0a * G0a;
        } else {
            float G0b = Gsh[w][cb];
            float Gab = Gsh[w][ca * 9 + cb];
            float Gbb = Gsh[w][cb * 9 + cb];
            det = G00 * (Gaa * Gbb - Gab * Gab)
                - G0a * (G0a * Gbb - Gab * G0b)
                + G0b * (G0a * Gab - Gaa * G0b);
        }
        score = valid ? (logf(det + 1e-6f) / (float)(sdim + 1)) : NEGV;
    }
    // softmax over scores via butterfly (lanes>=36 contribute -inf / 0)
    float mx = score;
    #pragma unroll
    for (int off = 32; off > 0; off >>= 1) mx = fmaxf(mx, __shfl_xor(mx, off, 64));
    float e = (lane < NCOMB) ? expf(score - mx) : 0.f;
    float sum = e;
    #pragma unroll
    for (int off = 32; off > 0; off >>= 1) sum += __shfl_xor(sum, off, 64);
    const bool hasValid = (mx > -1e29f);

    if (lane < NCOMB) {
        float prob = e / sum;
        float d0 = qdsh[w][0]  * 0.125f;
        float d1 = qdsh[w][ca] * 0.125f;
        float d2 = (sdim == 2) ? qdsh[w][cb] * 0.125f : -INFINITY;
        float m2 = fmaxf(fmaxf(d0, d1), d2);
        float e0 = expf(d0 - m2), e1 = expf(d1 - m2);
        float e2 = (sdim == 2) ? expf(d2 - m2) : 0.f;
        float inv = prob / (e0 + e1 + e2);
        float4 pw = {e0 * inv, e1 * inv, e2 * inv, 0.f};
        *(float4*)&PW[w][lane][0] = pw;
    }
    __syncthreads();

    // y[d], d = lane
    const float v0 = Vsh[w][0][lane];
    float y;
    if (!hasValid) {
        y = v0;
    } else {
        float acc = 0.f;
        #pragma unroll
        for (int c = 0; c < NCOMB; ++c) {
            float4 pw = *(const float4*)&PW[w][c][0];
            int a = C_SL0[c] + 1;
            int b = (C_SL1[c] < 0) ? 0 : C_SL1[c] + 1;   // pw.z == 0 when sdim==1
            acc += pw.x * v0 + pw.y * Vsh[w][a][lane] + pw.z * Vsh[w][b][lane];
        }
        y = acc;
    }
    const int bb = bh / Hn, h = bh % Hn;
    yflat[((size_t)(bb * Tn + i)) * Cn + h * HS + lane] = y;
}

extern "C" void kernel_launch(void* const* d_in, const int* in_sizes, int n_in,
                              void* d_out, int out_size, void* d_ws, size_t ws_size,
                              hipStream_t stream) {
    const float* x      = (const float*)d_in[0];
    const float* W_attn = (const float*)d_in[1];
    const float* b_attn = (const float*)d_in[2];
    const float* W_proj = (const float*)d_in[3];
    const float* b_proj = (const float*)d_in[4];
    float* out = (float*)d_out;

    float* ws = (float*)d_ws;
    const size_t per = (size_t)BH * Tn * HS;  // 786432 floats
    float* qh = ws;
    float* kh = ws + per;
    float* vh = ws + 2 * per;
    float* yf = ws + 3 * per;

    // zero the atomic-accumulated buffers (yf is fully overwritten by dpp -> no zero)
    hipMemsetAsync(qh, 0, 3 * per * sizeof(float), stream);
    hipMemsetAsync(out, 0, (size_t)out_size * sizeof(float), stream);

    // qkv projection: split-K x2 -> grid (36, 16, 2) = 1152 blocks, 24 slabs/slice
    gemm64<24, true><<<dim3(36, 16, 2), 256, 0, stream>>>(x, W_attn, b_attn, nullptr, qh, kh, vh);

    // dpp: one wave per (head, token), 4 consecutive tokens per block
    dpp_kernel<<<dim3(BH, Tn / 4), 256, 0, stream>>>(qh, kh, vh, yf);

    // output projection: split-K x4 -> grid (12, 16, 4) = 768 blocks, 12 slabs/slice
    gemm64<12, false><<<dim3(12, 16, 4), 256, 0, stream>>>(yf, W_proj, b_proj, out, nullptr, nullptr, nullptr);
}

// Round 5
// 230.788 us; speedup vs baseline: 1.2797x; 1.2797x over previous
//
#include <hip/hip_runtime.h>
#include <math.h>

#define Bn 2
#define Hn 12
#define Tn 512
#define Cn 768
#define HS 64
#define BH 24
#define MTOP 8
#define NCOMB 36
#define NEGV -1e30f

typedef __bf16 bf16x8 __attribute__((ext_vector_type(8)));
typedef float f32x4 __attribute__((ext_vector_type(4)));

// combo tables: slots (0..7) for size-1 (8 combos) then size-2 (28 combos), lexicographic
__device__ __constant__ int C_SL0[NCOMB] = {
  0,1,2,3,4,5,6,7,
  0,0,0,0,0,0,0,
  1,1,1,1,1,1,
  2,2,2,2,2,
  3,3,3,3,
  4,4,4,
  5,5,
  6};
__device__ __constant__ int C_SL1[NCOMB] = {
  -1,-1,-1,-1,-1,-1,-1,-1,
  1,2,3,4,5,6,7,
  2,3,4,5,6,7,
  3,4,5,6,7,
  4,5,6,7,
  5,6,7,
  6,7,
  7};

// gram pair tables: 45 pairs (a<=b) over 9 tokens
__device__ __constant__ int PA[45] = {
  0,0,0,0,0,0,0,0,0,
  1,1,1,1,1,1,1,1,
  2,2,2,2,2,2,2,
  3,3,3,3,3,3,
  4,4,4,4,4,
  5,5,5,5,
  6,6,6,
  7,7,
  8};
__device__ __constant__ int PB[45] = {
  0,1,2,3,4,5,6,7,8,
  1,2,3,4,5,6,7,8,
  2,3,4,5,6,7,8,
  3,4,5,6,7,8,
  4,5,6,7,8,
  5,6,7,8,
  6,7,8,
  7,8,
  8};

// ---------------- fp32 -> bf16 (RNE) convert ------------------------------------------
__global__ __launch_bounds__(256) void conv_bf(const float* __restrict__ s,
                                               unsigned short* __restrict__ d, int n) {
    int idx = blockIdx.x * 256 + threadIdx.x;
    if (idx < n) {
        unsigned u = __float_as_uint(s[idx]);
        d[idx] = (unsigned short)((u + 0x7fff + ((u >> 16) & 1)) >> 16);
    }
}

// ---------------- bf16 MFMA GEMM: out = A @ B^T + bias --------------------------------
// A: [M][K] bf16 row-major; B: [N][K] bf16 row-major (i.e. B^T input). out fp32.
// block = 4 waves, each wave a 32x32 tile (2x2 of 16x16x32 MFMA); block tile 64x64.
// SCATTER=true: out scattered to per-head v layout; false: flat [M][N].
template<bool SCATTER>
__global__ __launch_bounds__(256) void mfma_nt(const unsigned short* __restrict__ Abf,
                                               const unsigned short* __restrict__ Bbf,
                                               const float* __restrict__ bias,
                                               float* __restrict__ outp,
                                               int M, int N, int K) {
    const int wv = threadIdx.x >> 6;
    const int lane = threadIdx.x & 63;
    const int m0 = blockIdx.y * 64 + (wv >> 1) * 32;
    const int n0 = blockIdx.x * 64 + (wv & 1) * 32;
    const int r = lane & 15;
    const int kq = lane >> 4;          // 0..3 -> k offset kq*8 within the 32-k step
    f32x4 acc[2][2] = {};
    const unsigned short* arow0 = Abf + (size_t)(m0 + r) * K + kq * 8;
    const unsigned short* arow1 = arow0 + 16 * K;
    const unsigned short* brow0 = Bbf + (size_t)(n0 + r) * K + kq * 8;
    const unsigned short* brow1 = brow0 + 16 * K;
    for (int k = 0; k < K; k += 32) {
        bf16x8 a0 = *(const bf16x8*)(arow0 + k);
        bf16x8 a1 = *(const bf16x8*)(arow1 + k);
        bf16x8 b0 = *(const bf16x8*)(brow0 + k);
        bf16x8 b1 = *(const bf16x8*)(brow1 + k);
        acc[0][0] = __builtin_amdgcn_mfma_f32_16x16x32_bf16(a0, b0, acc[0][0], 0, 0, 0);
        acc[0][1] = __builtin_amdgcn_mfma_f32_16x16x32_bf16(a0, b1, acc[0][1], 0, 0, 0);
        acc[1][0] = __builtin_amdgcn_mfma_f32_16x16x32_bf16(a1, b0, acc[1][0], 0, 0, 0);
        acc[1][1] = __builtin_amdgcn_mfma_f32_16x16x32_bf16(a1, b1, acc[1][1], 0, 0, 0);
    }
    // D mapping (verified): col = lane&15, row = (lane>>4)*4 + rr
    #pragma unroll
    for (int im = 0; im < 2; ++im) {
        #pragma unroll
        for (int in = 0; in < 2; ++in) {
            #pragma unroll
            for (int rr = 0; rr < 4; ++rr) {
                int mm = m0 + im * 16 + kq * 4 + rr;
                int nn = n0 + in * 16 + r;
                float val = acc[im][in][rr] + bias[nn];
                if (!SCATTER) {
                    outp[(size_t)mm * N + nn] = val;
                } else {
                    int bb = mm >> 9, t = mm & 511;
                    int h = nn >> 6, d = nn & 63;
                    outp[((size_t)((bb * Hn) + h) * Tn + t) * HS + d] = val;
                }
            }
        }
    }
}

// ---------------- fp32 64x64-tile GEMM for q,k cols: direct store + scatter -----------
// C[m][n] = sum_k x[m][k]*W[n][k] + bias[n]; n in [0,1536) -> q (part 0) / k (part 1).
__global__ __launch_bounds__(256) void gemm_qk(const float* __restrict__ A,
                                               const float* __restrict__ W,
                                               const float* __restrict__ bias,
                                               float* __restrict__ qh,
                                               float* __restrict__ kh) {
    __shared__ float As[16][68];   // As[kk][m]
    __shared__ float Bs[16][68];   // Bs[kk][n]
    const int tn = blockIdx.x * 64;
    const int tm = blockIdx.y * 64;
    const int tid = threadIdx.x;
    const int tx = tid & 15;       // n dir
    const int ty = tid >> 4;       // m dir
    const int lm  = tid >> 2;      // staging row (0..63)
    const int lkc = (tid & 3) * 4; // staging k offset (0,4,8,12)

    const float* pA = A + (size_t)(tm + lm) * Cn + lkc;
    const float* pB = W + (size_t)(tn + lm) * Cn + lkc;
    float4 ra = *(const float4*)pA;
    float4 rb = *(const float4*)pB;

    float acc[4][4] = {};
    for (int k0 = 0; k0 < Cn; k0 += 16) {
        As[lkc+0][lm] = ra.x; As[lkc+1][lm] = ra.y; As[lkc+2][lm] = ra.z; As[lkc+3][lm] = ra.w;
        Bs[lkc+0][lm] = rb.x; Bs[lkc+1][lm] = rb.y; Bs[lkc+2][lm] = rb.z; Bs[lkc+3][lm] = rb.w;
        __syncthreads();
        if (k0 + 16 < Cn) {        // prefetch next K-slab
            ra = *(const float4*)(pA + k0 + 16);
            rb = *(const float4*)(pB + k0 + 16);
        }
        #pragma unroll
        for (int kk = 0; kk < 16; ++kk) {
            float4 a4 = *(const float4*)&As[kk][ty * 4];
            float4 b4 = *(const float4*)&Bs[kk][tx * 4];
            float am[4] = {a4.x, a4.y, a4.z, a4.w};
            float bn[4] = {b4.x, b4.y, b4.z, b4.w};
            #pragma unroll
            for (int um = 0; um < 4; ++um)
                #pragma unroll
                for (int un = 0; un < 4; ++un)
                    acc[um][un] += am[um] * bn[un];
        }
        __syncthreads();
    }

    float bv[4];
    #pragma unroll
    for (int un = 0; un < 4; ++un) bv[un] = bias[tn + tx * 4 + un];

    // 64-col tile lies entirely within one part (q or k) and one head
    const int part = tn / Cn;              // 0=q, 1=k
    const int c0 = tn - part * Cn;
    const int h = c0 >> 6;
    const int d = tx * 4;
    float* dst = (part == 0) ? qh : kh;
    #pragma unroll
    for (int um = 0; um < 4; ++um) {
        int m = tm + ty * 4 + um;
        int bb = m >> 9, t = m & 511;
        float4 o = {acc[um][0] + bv[0], acc[um][1] + bv[1],
                    acc[um][2] + bv[2], acc[um][3] + bv[3]};
        *(float4*)(dst + ((size_t)((bb * Hn) + h) * Tn + t) * HS + d) = o;
    }
}

// ---------------- DPP selection: one WAVE per token, 4 consecutive tokens/block -------
// K-prefix scanned via shared LDS chunks (4-way reuse), register-prefetch pipelined.
// Output y written directly as bf16 (feeds the bf16 MFMA proj).
__global__ __launch_bounds__(256, 4) void dpp_kernel(const float* __restrict__ qh,
                                                     const float* __restrict__ kh,
                                                     const float* __restrict__ vh,
                                                     unsigned short* __restrict__ yb) {
    const int bh = blockIdx.x;
    const int i0 = blockIdx.y * 4;
    const int w = threadIdx.x >> 6;
    const int lane = threadIdx.x & 63;
    const int i = i0 + w;

    __shared__ float Klds[64][68];     // K-chunk staging (17.4 KB)
    __shared__ float Ksh[4][9][68];    // selected K rows (b128 gram reads)
    __shared__ float Vsh[4][9][65];    // selected V rows (b32 lane-stride reads)
    __shared__ float Gsh[4][81];
    __shared__ float qdsh[4][12];
    __shared__ float PW[4][36][4];

    const float* qp    = qh + (size_t)(bh * Tn + i) * HS;
    const float* kbase = kh + (size_t)bh * Tn * HS;
    const float* vbase = vh + (size_t)bh * Tn * HS;

    // q_i resident in registers for the whole sim phase
    float4 qv[16];
    #pragma unroll
    for (int t = 0; t < 16; ++t) qv[t] = ((const float4*)qp)[t];

    float sv[8];
    #pragma unroll
    for (int r = 0; r < 8; ++r) sv[r] = -INFINITY;

    const int cmax = (i0 + 3) >> 6;    // block-uniform
    const int rmax = i >> 6;

    // software-pipelined chunk staging: prefetch chunk c+1 while computing chunk c
    float4 pre[4];
    {
        const float4* src = (const float4*)kbase;
        #pragma unroll
        for (int u = 0; u < 4; ++u) pre[u] = src[threadIdx.x + u * 256];
    }
    #pragma unroll
    for (int c = 0; c < 8; ++c) {
        if (c <= cmax) {
            #pragma unroll
            for (int u = 0; u < 4; ++u) {
                int e = threadIdx.x + u * 256;
                *(float4*)&Klds[e >> 4][(e & 15) * 4] = pre[u];
            }
            __syncthreads();
            if (c + 1 <= cmax) {
                const float4* src = (const float4*)(kbase + (size_t)(c + 1) * 64 * HS);
                #pragma unroll
                for (int u = 0; u < 4; ++u) pre[u] = src[threadIdx.x + u * 256];
            }
            if (c <= rmax) {
                const int j = c * 64 + lane;
                const float4* kr = (const float4*)&Klds[lane][0];
                float acc = 0.f;
                #pragma unroll
                for (int t = 0; t < 16; ++t) {
                    float4 kv = kr[t];
                    acc += kv.x * qv[t].x; acc += kv.y * qv[t].y;
                    acc += kv.z * qv[t].z; acc += kv.w * qv[t].w;
                }
                sv[c] = (j <= i) ? acc : -INFINITY;
            }
            __syncthreads();
        }
    }

    // qd0 = sim[i] = k_i . q_i
    float qd0 = 0.f;
    #pragma unroll
    for (int c = 0; c < 8; ++c) {
        float t = __shfl(sv[c], i & 63, 64);
        if (c == rmax) qd0 = t;
    }

    // top-8: 8 in-register butterfly argmax passes (value desc, tie -> lower index)
    float topv[8]; int topi[8];
    #pragma unroll
    for (int p = 0; p < MTOP; ++p) {
        float bv = -INFINITY; int bi = 0x7fffffff;
        #pragma unroll
        for (int r = 0; r < 8; ++r) {
            int j = r * 64 + lane;
            float v = sv[r];
            if (v > bv || (v == bv && j < bi)) { bv = v; bi = j; }
        }
        #pragma unroll
        for (int off = 32; off > 0; off >>= 1) {
            float ov = __shfl_xor(bv, off, 64);
            int   oi = __shfl_xor(bi, off, 64);
            if (ov > bv || (ov == bv && oi < bi)) { bv = ov; bi = oi; }
        }
        topv[p] = bv; topi[p] = bi;
        const int rs = bi >> 6, ls = bi & 63;
        #pragma unroll
        for (int r = 0; r < 8; ++r)
            if (r == rs && lane == ls) sv[r] = -INFINITY;
    }

    // validity bitmask per slot (wave-uniform)
    const int n_cand = (i + 1 < MTOP) ? (i + 1) : MTOP;
    int vmask = 0;
    #pragma unroll
    for (int s = 0; s < MTOP; ++s)
        if (s < n_cand && topi[s] != i) vmask |= (1 << s);

    // stage selected K/V rows {i} U top_idx (coalesced, lane = d)
    #pragma unroll
    for (int a = 0; a < 9; ++a) {
        int t = (a == 0) ? i : topi[a - 1];
        Ksh[w][a][lane] = kbase[(size_t)t * HS + lane];
        Vsh[w][a][lane] = vbase[(size_t)t * HS + lane];
    }
    if (lane < 9) {
        float val = qd0;
        #pragma unroll
        for (int p = 0; p < 8; ++p) if (lane == p + 1) val = topv[p];
        qdsh[w][lane] = val;
    }
    __syncthreads();

    // gram: lane l < 45 computes pair (PA[l], PB[l])
    if (lane < 45) {
        const int a = PA[lane], b = PB[lane];
        const float4* rka = (const float4*)&Ksh[w][a][0];
        const float4* rkb = (const float4*)&Ksh[w][b][0];
        float acc = 0.f;
        #pragma unroll
        for (int t = 0; t < 16; ++t) {
            float4 fa = rka[t], fb = rkb[t];
            acc += fa.x * fb.x; acc += fa.y * fb.y;
            acc += fa.z * fb.z; acc += fa.w * fb.w;
        }
        Gsh[w][a * 9 + b] = acc;
        Gsh[w][b * 9 + a] = acc;
    }
    __syncthreads();

    // combos on lanes 0..35
    float score = -INFINITY;
    int ca = 0, cb = 0, sdim = 1;
    if (lane < NCOMB) {
        const int sl0 = C_SL0[lane], sl1 = C_SL1[lane];
        sdim = (sl1 < 0) ? 1 : 2;
        ca = sl0 + 1;
        cb = (sl1 < 0) ? 0 : sl1 + 1;
        bool valid = ((vmask >> sl0) & 1);
        if (sdim == 2) valid = valid && ((vmask >> sl1) & 1);
        float G00 = Gsh[w][0];
        float Gaa = Gsh[w][ca * 9 + ca];
        float G0a = Gsh[w][ca];
        float det;
        if (sdim == 1) {
            det = G00 * Gaa - G0a * G0a;
        } else {
            float G0b = Gsh[w][cb];
            float Gab = Gsh[w][ca * 9 + cb];
            float Gbb = Gsh[w][cb * 9 + cb];
            det = G00 * (Gaa * Gbb - Gab * Gab)
                - G0a * (G0a * Gbb - Gab * G0b)
                + G0b * (G0a * Gab - Gaa * G0b);
        }
        score = valid ? (logf(det + 1e-6f) / (float)(sdim + 1)) : NEGV;
    }
    // softmax over scores via butterfly (lanes>=36 contribute -inf / 0)
    float mx = score;
    #pragma unroll
    for (int off = 32; off > 0; off >>= 1) mx = fmaxf(mx, __shfl_xor(mx, off, 64));
    float e = (lane < NCOMB) ? expf(score - mx) : 0.f;
    float sum = e;
    #pragma unroll
    for (int off = 32; off > 0; off >>= 1) sum += __shfl_xor(sum, off, 64);
    const bool hasValid = (mx > -1e29f);

    if (lane < NCOMB) {
        float prob = e / sum;
        float d0 = qdsh[w][0]  * 0.125f;
        float d1 = qdsh[w][ca] * 0.125f;
        float d2 = (sdim == 2) ? qdsh[w][cb] * 0.125f : -INFINITY;
        float m2 = fmaxf(fmaxf(d0, d1), d2);
        float e0 = expf(d0 - m2), e1 = expf(d1 - m2);
        float e2 = (sdim == 2) ? expf(d2 - m2) : 0.f;
        float inv = prob / (e0 + e1 + e2);
        float4 pw = {e0 * inv, e1 * inv, e2 * inv, 0.f};
        *(float4*)&PW[w][lane][0] = pw;
    }
    __syncthreads();

    // y[d], d = lane
    const float v0 = Vsh[w][0][lane];
    float y;
    if (!hasValid) {
        y = v0;
    } else {
        float acc = 0.f;
        #pragma unroll
        for (int c = 0; c < NCOMB; ++c) {
            float4 pw = *(const float4*)&PW[w][c][0];
            int a = C_SL0[c] + 1;
            int b = (C_SL1[c] < 0) ? 0 : C_SL1[c] + 1;   // pw.z == 0 when sdim==1
            acc += pw.x * v0 + pw.y * Vsh[w][a][lane] + pw.z * Vsh[w][b][lane];
        }
        y = acc;
    }
    const int bb = bh / Hn, h = bh % Hn;
    // bf16 (RNE) store -> proj MFMA input
    unsigned u = __float_as_uint(y);
    yb[((size_t)(bb * Tn + i)) * Cn + h * HS + lane] =
        (unsigned short)((u + 0x7fff + ((u >> 16) & 1)) >> 16);
}

extern "C" void kernel_launch(void* const* d_in, const int* in_sizes, int n_in,
                              void* d_out, int out_size, void* d_ws, size_t ws_size,
                              hipStream_t stream) {
    const float* x      = (const float*)d_in[0];
    const float* W_attn = (const float*)d_in[1];
    const float* b_attn = (const float*)d_in[2];
    const float* W_proj = (const float*)d_in[3];
    const float* b_proj = (const float*)d_in[4];
    float* out = (float*)d_out;

    float* ws = (float*)d_ws;
    const size_t per = (size_t)BH * Tn * HS;            // 786432 floats
    float* qh = ws;
    float* kh = ws + per;
    float* vh = ws + 2 * per;
    // bf16 scratch (aliased to save ws):
    //   buf1: x_bf before dpp, then y_bf (x_bf dead after v-MFMA)
    //   buf2: Wv_bf before v-MFMA, then Wp_bf (converted after v-MFMA)
    unsigned short* buf1 = (unsigned short*)(ws + 3 * per);          // 786432 ushorts
    unsigned short* buf2 = buf1 + per;                                // 589824 ushorts
    // total ws: 9 MB + 1.5 MB + 1.125 MB = 11.625 MB (r1 used 12.58 MB -> fits)

    const int NV = Cn * Cn;        // 589824 (one weight part)
    const int NX = Bn * Tn * Cn;   // 786432

    // 1) convert x and Wv (= W_attn rows 1536..2303) to bf16
    conv_bf<<<dim3((NX + 255) / 256), 256, 0, stream>>>(x, buf1, NX);
    conv_bf<<<dim3((NV + 255) / 256), 256, 0, stream>>>(W_attn + (size_t)2 * Cn * Cn, buf2, NV);

    // 2) v = x @ Wv^T + bv via bf16 MFMA, scattered to per-head vh (fp32)
    mfma_nt<true><<<dim3(12, 16), 256, 0, stream>>>(buf1, buf2, b_attn + 2 * Cn, vh,
                                                    Bn * Tn, Cn, Cn);

    // 3) convert Wp into buf2 (Wv dead)
    conv_bf<<<dim3((NV + 255) / 256), 256, 0, stream>>>(W_proj, buf2, NV);

    // 4) q,k = x @ W_qk^T + b via fp32 tiled GEMM (flip-sensitive path stays fp32)
    gemm_qk<<<dim3(24, 16), 256, 0, stream>>>(x, W_attn, b_attn, qh, kh);

    // 5) dpp: one wave per (head, token); writes y as bf16 into buf1 (x_bf dead)
    dpp_kernel<<<dim3(BH, Tn / 4), 256, 0, stream>>>(qh, kh, vh, buf1);

    // 6) out = y @ Wp^T + bp via bf16 MFMA, flat store
    mfma_nt<false><<<dim3(12, 16), 256, 0, stream>>>(buf1, buf2, b_proj, out,
                                                     Bn * Tn, Cn, Cn);
}